// Round 15
// baseline (2080.612 us; speedup 1.0000x reference)
//
#include <hip/hip_runtime.h>

// ---------------- constants (match reference) ----------------
constexpr int L_ = 6, C_ = 192, FC_ = 768, H_ = 2, KC_ = 96, KW = 3, W_ = 4;
constexpr int B_ = 4, T_ = 2048;
constexpr int NC_ = 8, CS_ = T_ / NC_;   // split-S chunks for attention
constexpr float SCALE_ = 0.102062072615965696f; // 96^-0.5
constexpr float MB_ = 16.0f;             // fixed softmax rebase (overflow at S>104)

typedef unsigned short u16;
typedef unsigned int u32;
typedef short s16x8 __attribute__((ext_vector_type(8)));
typedef float f32x4 __attribute__((ext_vector_type(4)));
struct alignas(16) U4 { u32 x, y, z, w; };

#define MEMFENCE asm volatile("" ::: "memory")

// ---------------- static device scratch ----------------
__device__ alignas(256) float g_xf [B_ * T_ * C_];    // fp32 residual [B][T][C]
__device__ alignas(256) u16   g_xb [B_ * T_ * C_];    // bf16 residual
__device__ alignas(256) u16   g_qt [B_ * T_ * C_];    // q (pre-scaled) [B][T][C]
__device__ alignas(256) u16   g_kt [B_ * T_ * C_];    // k [B][T][C]
__device__ alignas(256) u16   g_vv [B_ * T_ * C_];    // v [B][C][T]
__device__ alignas(256) u16   g_aob[B_ * T_ * C_];    // attn out bf16
__device__ alignas(256) float g_dpj[B_ * T_ * C_];    // fp32 delta
__device__ alignas(256) u16   g_hh [B_ * T_ * FC_];   // FFN hidden bf16
__device__ alignas(256) u16   g_wq [L_ * C_ * C_];    // bf16 weights
__device__ alignas(256) u16   g_wk [L_ * C_ * C_];
__device__ alignas(256) u16   g_wv [L_ * C_ * C_];
__device__ alignas(256) u16   g_wo [L_ * C_ * C_];
__device__ alignas(256) u16   g_r1 [L_ * KW * FC_ * C_];  // conv1 repacked [k][f][c]
__device__ alignas(256) u16   g_r2 [L_ * KW * C_ * FC_];  // conv2 repacked [k][o][f]
// attention split-S partials: part = ((b*H+h)*128+strip)*NC+chunk
__device__ alignas(256) float g_Op [B_ * H_ * 128 * NC_ * 16 * KC_]; // 50 MB
__device__ alignas(256) float g_ml [B_ * H_ * 128 * NC_ * 16];       // l per row
// per-layer precomputed relative terms: [B][H][T][9]
__device__ alignas(256) float g_rqk[B_ * H_ * T_ * 9];  // q . erk_j
__device__ alignas(256) float g_wds[B_ * H_ * T_ * 9];  // q . k_{t+j-4} + rqk (-1e30 OOB)

#define DEV static __device__ __forceinline__

DEV float b2f(u16 v) { return __builtin_bit_cast(float, (u32)(((u32)v) << 16)); }
DEV u16 f2b(float f) {
    u32 u = __builtin_bit_cast(u32, f);
    u32 r = (u + 0x7FFFu + ((u >> 16) & 1u)) >> 16;
    return (u16)r;
}
DEV f32x4 mfma16(U4 a, U4 b, f32x4 c) {
    return __builtin_amdgcn_mfma_f32_16x16x32_bf16(
        __builtin_bit_cast(s16x8, a), __builtin_bit_cast(s16x8, b), c, 0, 0, 0);
}

// ---------------- proj weights f32 -> bf16 (same layout) --------------------
__global__ void convw_kernel(const float* __restrict__ wq, const float* __restrict__ wk,
                             const float* __restrict__ wv, const float* __restrict__ wo,
                             u16* __restrict__ dq, u16* __restrict__ dk,
                             u16* __restrict__ dv, u16* __restrict__ dwo) {
    const int NW = L_ * C_ * C_;
    int i = blockIdx.x * 256 + threadIdx.x;
    int which = i / NW, j = i - which * NW;
    const float* s = (which == 0) ? wq : (which == 1) ? wk : (which == 2) ? wv : wo;
    u16* d = (which == 0) ? dq : (which == 1) ? dk : (which == 2) ? dv : dwo;
    d[j] = f2b(s[j]);
}

// ---------------- conv weights f32 -> bf16, contiguous-c per tap ------------
__global__ void repack_kernel(const float* __restrict__ fw1, const float* __restrict__ fw2,
                              u16* __restrict__ r1, u16* __restrict__ r2) {
    int i = blockIdx.x * 256 + threadIdx.x;
    const int E1 = L_ * KW * FC_ * C_;
    if (i < E1) {
        int c = i % C_; int tmp = i / C_;
        int f = tmp % FC_; tmp /= FC_;
        int k = tmp % KW; int l = tmp / KW;
        r1[i] = f2b(fw1[((l * FC_ + f) * C_ + c) * KW + k]);
    } else {
        int j = i - E1;
        int f = j % FC_; int tmp = j / FC_;
        int o = tmp % C_; tmp /= C_;
        int k = tmp % KW; int l = tmp / KW;
        r2[j] = f2b(fw2[((l * C_ + o) * FC_ + f) * KW + k]);
    }
}

// ---------------- init: x[B,C,T] f32 -> xf fp32 / xb bf16 [B,T,C] (masked) --
__global__ void init_kernel(const float* __restrict__ x, const float* __restrict__ msk,
                            float* __restrict__ xf, u16* __restrict__ xb) {
    int i = blockIdx.x * 256 + threadIdx.x;
    int c = i % C_; int tmp = i / C_; int t = tmp % T_; int b = tmp / T_;
    float v = x[((long long)b * C_ + c) * T_ + t] * msk[b * T_ + t];
    xf[i] = v; xb[i] = f2b(v);
}

// ---------------- out: xf [B,T,C] -> out[B,C,T] FP32 (masked) ---------------
__global__ void out_kernel(const float* __restrict__ xf, const float* __restrict__ msk,
                           float* __restrict__ out) {
    int i = blockIdx.x * 256 + threadIdx.x;
    int t = i % T_; int tmp = i / T_; int c = tmp % C_; int b = tmp / C_;
    float v = xf[((long long)b * T_ + t) * C_ + c] * msk[b * T_ + t];
    if (!(v == v)) v = 0.0f;
    out[i] = v;
}

// ---------------- LayerNorm over C: xf = LN(xf + delta); xb = bf16(xf) ------
__global__ __launch_bounds__(256) void ln_kernel(float* __restrict__ xf,
                                                 const float* __restrict__ delta,
                                                 u16* __restrict__ xb,
                                                 const float* __restrict__ g,
                                                 const float* __restrict__ be) {
    int pos = blockIdx.x * 4 + (threadIdx.x >> 6);
    int lane = threadIdx.x & 63;
    long long base = (long long)pos * C_;
    float u[3]; float s = 0.f;
#pragma unroll
    for (int i = 0; i < 3; ++i) {
        int c = lane + i * 64;
        float v = xf[base + c] + delta[base + c];
        u[i] = v; s += v;
    }
#pragma unroll
    for (int d = 1; d < 64; d <<= 1) s += __shfl_xor(s, d, 64);
    float mean = s * (1.0f / C_);
    float ss = 0.f;
#pragma unroll
    for (int i = 0; i < 3; ++i) { float dv = u[i] - mean; ss += dv * dv; }
#pragma unroll
    for (int d = 1; d < 64; d <<= 1) ss += __shfl_xor(ss, d, 64);
    float var = fmaxf(ss * (1.0f / C_), 0.0f);
    float rs = rsqrtf(var + 1e-5f);
#pragma unroll
    for (int i = 0; i < 3; ++i) {
        int c = lane + i * 64;
        float y = (u[i] - mean) * rs * g[c] + be[c];
        xf[base + c] = y; xb[base + c] = f2b(y);
    }
}

// ---------------- generic MFMA GEMM, 64x64 wave tile ----------------
struct GemmTask {
    const u16* A; const u16* B; const float* bias;
    float* Df; u16* Db;
    long long aBatch, bBatch, dBatch, segB;
    int lda, ldb, ldd;
    int M, N, Kd, nShift;
    float alpha; int flags; // 1 = relu, 2 = bias indexed by row (else col)
    int tilesM, tileBase;   // tilesM = M/64
};

__global__ __launch_bounds__(256) void gemm_kernel(GemmTask ta, GemmTask tb, GemmTask tc,
                                                   int nTasks, int totalTiles) {
    int wid = blockIdx.x * 4 + (threadIdx.x >> 6);
    if (wid >= totalTiles) return;
    GemmTask t = ta;
    if (nTasks > 1 && wid >= tb.tileBase) t = tb;
    if (nTasks > 2 && wid >= tc.tileBase) t = tc;
    int tid = wid - t.tileBase;
    int tm = tid % t.tilesM, tn = tid / t.tilesM;
    int z = blockIdx.y;
    int lane = threadIdx.x & 63, l15 = lane & 15, quad = lane >> 4;
    const u16* A = t.A + (long long)z * t.aBatch;
    const u16* Bb = t.B + (long long)z * t.bBatch;
    int m0 = tm * 64, n0 = tn * 64;
    f32x4 acc[4][4] = {};
    int cb = quad * 8;
    for (int sh = 0; sh < t.nShift; ++sh) {
        int rowOff = sh - (t.nShift >> 1);
        const u16* Bs = Bb + (long long)sh * t.segB;
        const u16* ar[4]; bool av[4];
        const u16* br[4];
#pragma unroll
        for (int mi = 0; mi < 4; ++mi) {
            int r = m0 + l15 + 16 * mi + rowOff;
            av[mi] = (unsigned)r < (unsigned)t.M;
            ar[mi] = A + (long long)r * t.lda + cb;
        }
#pragma unroll
        for (int ni = 0; ni < 4; ++ni)
            br[ni] = Bs + (long long)(n0 + 16 * ni + l15) * t.ldb + cb;
        for (int kk = 0; kk < t.Kd; kk += 32) {
            U4 a[4], b[4];
#pragma unroll
            for (int mi = 0; mi < 4; ++mi)
                a[mi] = av[mi] ? *(const U4*)(ar[mi] + kk) : U4{0, 0, 0, 0};
#pragma unroll
            for (int ni = 0; ni < 4; ++ni)
                b[ni] = *(const U4*)(br[ni] + kk);
#pragma unroll
            for (int mi = 0; mi < 4; ++mi)
#pragma unroll
                for (int ni = 0; ni < 4; ++ni)
                    acc[mi][ni] = mfma16(a[mi], b[ni], acc[mi][ni]);
        }
    }
#pragma unroll
    for (int mi = 0; mi < 4; ++mi)
#pragma unroll
        for (int ni = 0; ni < 4; ++ni) {
            int col = n0 + ni * 16 + l15;
#pragma unroll
            for (int reg = 0; reg < 4; ++reg) {
                int row = m0 + mi * 16 + quad * 4 + reg;
                float bb = t.bias[(t.flags & 2) ? row : col];
                float val = (acc[mi][ni][reg] + bb) * t.alpha;
                if (t.flags & 1) val = fmaxf(val, 0.0f);
                long long o = (long long)z * t.dBatch + (long long)row * t.ldd + col;
                if (t.Df) t.Df[o] = val; else t.Db[o] = f2b(val);
            }
        }
}

// ---------------- per-layer relative-term precompute ----------------
__global__ __launch_bounds__(256) void rqwd_kernel(const u16* __restrict__ q,
                                                   const u16* __restrict__ k,
                                                   const float* __restrict__ erk,
                                                   float* __restrict__ rqk,
                                                   float* __restrict__ wds) {
    int i = blockIdx.x * 256 + threadIdx.x;        // over B*H*T*9
    int j = i % 9; int tmp = i / 9;
    int t = tmp % T_; tmp /= T_;
    int h = tmp & 1; int b = tmp >> 1;
    const u16* qr = q + ((long long)b * T_ + t) * C_ + h * KC_;
    const float* er = erk + j * KC_;
    float s1 = 0.f;
    for (int c = 0; c < KC_; ++c) s1 += b2f(qr[c]) * er[c];
    rqk[i] = s1;
    int s2 = t + j - W_;
    float wd = -1e30f;
    if (s2 >= 0 && s2 < T_) {
        const u16* kr = k + ((long long)b * T_ + s2) * C_ + h * KC_;
        float d = 0.f;
        for (int c = 0; c < KC_; ++c) d += b2f(qr[c]) * b2f(kr[c]);
        wd = d + s1;
    }
    wds[i] = wd;
}

// ---------------- split-S attention, fixed-rebase, compiler-fenced ----------
__global__ __launch_bounds__(256) void attn_part(const u16* __restrict__ q,
                                                 const u16* __restrict__ k,
                                                 const u16* __restrict__ v,
                                                 float* __restrict__ Op,
                                                 float* __restrict__ ml,
                                                 const float* __restrict__ rqk) {
    __shared__ alignas(64) u16 Pl[4][16][48];
    __shared__ float rqc[4][16][12];

    int wib = threadIdx.x >> 6;
    int lane = threadIdx.x & 63, l15 = lane & 15, quad = lane >> 4;
    int w = blockIdx.x * 4 + wib;                 // ((b*H+h)*128+strip)*NC+chunk
    int chunk = w & (NC_ - 1);
    int strip = (w >> 3) & 127;
    int h = (w >> 10) & 1;
    int b = w >> 11;
    int t0 = strip * 16;
    int sbase = chunk * CS_;
    const u16* qp = q + ((long long)b * T_ + t0) * C_ + h * KC_;
    const u16* kp = k + (long long)b * T_ * C_ + h * KC_;
    const u16* vp = v + ((long long)b * C_ + h * KC_) * T_;

    const float* rq = rqk + (((long long)(b * H_ + h)) * T_ + t0) * 9;
    for (int idx = lane; idx < 144; idx += 64) {
        int r = idx / 9, j = idx - r * 9;
        rqc[wib][r][j] = rq[idx];
    }
    __syncthreads();   // once, outside hot loop

    U4 aq0 = *(const U4*)(qp + l15 * C_ + quad * 8);
    U4 aq1 = *(const U4*)(qp + l15 * C_ + 32 + quad * 8);
    U4 aq2 = *(const U4*)(qp + l15 * C_ + 64 + quad * 8);
    U4 ones{0x3F803F80u, 0x3F803F80u, 0x3F803F80u, 0x3F803F80u}; // bf16 1.0 x8

    f32x4 O[7] = {};   // [0..5] = output cols, [6] = row-sum l

    for (int s0 = sbase; s0 < sbase + CS_; s0 += 32) {
        f32x4 S[2];
#pragma unroll
        for (int sub = 0; sub < 2; ++sub) {
            const u16* kr = kp + (long long)(s0 + sub * 16 + l15) * C_ + quad * 8;
            f32x4 a = {0.f, 0.f, 0.f, 0.f};
            a = mfma16(aq0, *(const U4*)(kr), a);
            a = mfma16(aq1, *(const U4*)(kr + 32), a);
            a = mfma16(aq2, *(const U4*)(kr + 64), a);
            int s = s0 + sub * 16 + l15;
#pragma unroll
            for (int reg = 0; reg < 4; ++reg) {
                int t = t0 + quad * 4 + reg;
                int d = s - t;
                if (d >= -W_ && d <= W_) a[reg] += rqc[wib][quad * 4 + reg][d + W_];
            }
            S[sub] = a;
        }
#pragma unroll
        for (int sub = 0; sub < 2; ++sub)
#pragma unroll
            for (int reg = 0; reg < 4; ++reg)
                Pl[wib][quad * 4 + reg][sub * 16 + l15] = f2b(__expf(S[sub][reg] - MB_));
        MEMFENCE;   // RAW: stores above must not sink below the load
        U4 pf = *(const U4*)(&Pl[wib][l15][quad * 8]);
        MEMFENCE;   // WAR: next iteration's stores must not hoist above the load
#pragma unroll
        for (int dt = 0; dt < 6; ++dt) {
            const u16* vr = vp + (long long)(dt * 16 + l15) * T_ + s0 + quad * 8;
            O[dt] = mfma16(pf, *(const U4*)(vr), O[dt]);
        }
        O[6] = mfma16(pf, ones, O[6]);
    }

    float* Od = Op + (long long)w * 16 * KC_;
#pragma unroll
    for (int dt = 0; dt < 6; ++dt) {
        int col = dt * 16 + l15;
#pragma unroll
        for (int reg = 0; reg < 4; ++reg) {
            int row = quad * 4 + reg;
            Od[row * KC_ + col] = O[dt][reg];
        }
    }
    if (l15 == 0) {
#pragma unroll
        for (int reg = 0; reg < 4; ++reg)
            ml[(long long)w * 16 + quad * 4 + reg] = O[6][reg];
    }
}

// ---------------- combine (plain sum) + window-V epilogue -------------------
__global__ __launch_bounds__(256) void attn_comb(const float* __restrict__ Op,
                                                 const float* __restrict__ ml,
                                                 const float* __restrict__ wds,
                                                 u16* __restrict__ ao,
                                                 const float* __restrict__ erv) {
    __shared__ float lrow[4][16];
    __shared__ float pw[4][16][12];

    int wib = threadIdx.x >> 6, lane = threadIdx.x & 63;
    int w = blockIdx.x * 4 + wib;                 // (b*H+h)*128+strip
    int strip = w & 127, h = (w >> 7) & 1, b = w >> 8;
    int t0 = strip * 16;
    u16* aop = ao + ((long long)b * T_ + t0) * C_ + h * KC_;

    if (lane < 16) {
        float l = 0.f;
#pragma unroll
        for (int c4 = 0; c4 < NC_; ++c4)
            l += ml[(long long)(w * NC_ + c4) * 16 + lane];
        lrow[wib][lane] = l;
    }
    const float* wd = wds + (((long long)(b * H_ + h)) * T_ + t0) * 9;
    for (int idx = lane; idx < 144; idx += 64) {
        int r = idx / 9, j = idx - r * 9;
        pw[wib][r][j] = __expf(wd[idx] - MB_);    // 0 for OOB (-1e30)
    }
    __syncthreads();

    const float* Ob = Op + (long long)(w * NC_) * 16 * KC_;
    for (int idx = lane; idx < 16 * KC_; idx += 64) {
        int r = idx / KC_, c = idx - r * KC_;
        float acc = 0.f;
#pragma unroll
        for (int c4 = 0; c4 < NC_; ++c4)
            acc += Ob[(long long)c4 * 16 * KC_ + idx];
#pragma unroll
        for (int j = 0; j < 9; ++j) acc += pw[wib][r][j] * erv[j * KC_ + c];
        aop[(long long)r * C_ + c] = f2b(acc / lrow[wib][r]);
    }
}

// ---------------- host orchestration ----------------
extern "C" void kernel_launch(void* const* d_in, const int* in_sizes, int n_in,
                              void* d_out, int out_size, void* d_ws, size_t ws_size,
                              hipStream_t stream) {
    const float* x   = (const float*)d_in[0];
    const float* msk = (const float*)d_in[1];
    const float* Wq  = (const float*)d_in[2];
    const float* bq  = (const float*)d_in[3];
    const float* Wk  = (const float*)d_in[4];
    const float* bk  = (const float*)d_in[5];
    const float* Wv  = (const float*)d_in[6];
    const float* bv  = (const float*)d_in[7];
    const float* Wo  = (const float*)d_in[8];
    const float* bo  = (const float*)d_in[9];
    const float* erk = (const float*)d_in[10];
    const float* erv = (const float*)d_in[11];
    const float* g1  = (const float*)d_in[12];
    const float* be1 = (const float*)d_in[13];
    const float* fw1 = (const float*)d_in[14];
    const float* fb1 = (const float*)d_in[15];
    const float* fw2 = (const float*)d_in[16];
    const float* fb2 = (const float*)d_in[17];
    const float* g2  = (const float*)d_in[18];
    const float* be2 = (const float*)d_in[19];

    float *xf, *dpj, *Op, *ml, *rqk, *wds;
    u16 *xb, *qt, *kt, *vv, *aob, *hh, *wqb, *wkb, *wvb, *wob, *r1, *r2;
    hipGetSymbolAddress((void**)&xf,  HIP_SYMBOL(g_xf));
    hipGetSymbolAddress((void**)&xb,  HIP_SYMBOL(g_xb));
    hipGetSymbolAddress((void**)&qt,  HIP_SYMBOL(g_qt));
    hipGetSymbolAddress((void**)&kt,  HIP_SYMBOL(g_kt));
    hipGetSymbolAddress((void**)&vv,  HIP_SYMBOL(g_vv));
    hipGetSymbolAddress((void**)&aob, HIP_SYMBOL(g_aob));
    hipGetSymbolAddress((void**)&dpj, HIP_SYMBOL(g_dpj));
    hipGetSymbolAddress((void**)&hh,  HIP_SYMBOL(g_hh));
    hipGetSymbolAddress((void**)&wqb, HIP_SYMBOL(g_wq));
    hipGetSymbolAddress((void**)&wkb, HIP_SYMBOL(g_wk));
    hipGetSymbolAddress((void**)&wvb, HIP_SYMBOL(g_wv));
    hipGetSymbolAddress((void**)&wob, HIP_SYMBOL(g_wo));
    hipGetSymbolAddress((void**)&r1,  HIP_SYMBOL(g_r1));
    hipGetSymbolAddress((void**)&r2,  HIP_SYMBOL(g_r2));
    hipGetSymbolAddress((void**)&Op,  HIP_SYMBOL(g_Op));
    hipGetSymbolAddress((void**)&ml,  HIP_SYMBOL(g_ml));
    hipGetSymbolAddress((void**)&rqk, HIP_SYMBOL(g_rqk));
    hipGetSymbolAddress((void**)&wds, HIP_SYMBOL(g_wds));

    convw_kernel<<<dim3(4 * L_ * C_ * C_ / 256), 256, 0, stream>>>(Wq, Wk, Wv, Wo,
                                                                   wqb, wkb, wvb, wob);
    repack_kernel<<<dim3(2 * L_ * KW * FC_ * C_ / 256), 256, 0, stream>>>(fw1, fw2, r1, r2);
    init_kernel<<<dim3((B_ * T_ * C_) / 256), 256, 0, stream>>>(x, msk, xf, xb);

    for (int i = 0; i < L_; ++i) {
        const float* erkl = erk + (size_t)i * (2 * W_ + 1) * KC_;
        const float* ervl = erv + (size_t)i * (2 * W_ + 1) * KC_;

        // ---- fused q/k/v projections (3 tasks, one launch; 64x64 tiles) ----
        GemmTask tq{};
        tq.A = xb; tq.aBatch = (long long)T_ * C_; tq.lda = C_;
        tq.B = wqb + (size_t)i * C_ * C_; tq.bBatch = 0; tq.ldb = C_; tq.segB = 0;
        tq.bias = bq + i * C_;
        tq.Df = nullptr; tq.Db = qt; tq.dBatch = (long long)T_ * C_; tq.ldd = C_;
        tq.M = T_; tq.N = C_; tq.Kd = C_; tq.nShift = 1;
        tq.alpha = SCALE_; tq.flags = 0; tq.tilesM = T_ / 64; tq.tileBase = 0;

        GemmTask tkk = tq;
        tkk.B = wkb + (size_t)i * C_ * C_; tkk.bias = bk + i * C_;
        tkk.Db = kt; tkk.alpha = 1.f;
        tkk.tileBase = (T_ / 64) * (C_ / 64);

        GemmTask tv{};
        tv.A = wvb + (size_t)i * C_ * C_; tv.aBatch = 0; tv.lda = C_;
        tv.B = xb; tv.bBatch = (long long)T_ * C_; tv.ldb = C_; tv.segB = 0;
        tv.bias = bv + i * C_;
        tv.Df = nullptr; tv.Db = vv; tv.dBatch = (long long)C_ * T_; tv.ldd = T_;
        tv.M = C_; tv.N = T_; tv.Kd = C_; tv.nShift = 1;
        tv.alpha = 1.f; tv.flags = 2; tv.tilesM = C_ / 64;
        tv.tileBase = 2 * (T_ / 64) * (C_ / 64);

        int totQKV = 3 * (T_ / 64) * (C_ / 64);
        gemm_kernel<<<dim3((totQKV + 3) / 4, B_), 256, 0, stream>>>(tq, tkk, tv, 3, totQKV);

        // ---- rel-term precompute + split-S attention ----
        rqwd_kernel<<<dim3(B_ * H_ * T_ * 9 / 256), 256, 0, stream>>>(qt, kt, erkl, rqk, wds);
        attn_part<<<dim3(B_ * H_ * 128 * NC_ / 4), 256, 0, stream>>>(qt, kt, vv, Op, ml, rqk);
        attn_comb<<<dim3(B_ * H_ * 128 / 4), 256, 0, stream>>>(Op, ml, wds, aob, ervl);

        // ---- output projection (fp32 out) ----
        GemmTask to{};
        to.A = aob; to.aBatch = (long long)T_ * C_; to.lda = C_;
        to.B = wob + (size_t)i * C_ * C_; to.bBatch = 0; to.ldb = C_; to.segB = 0;
        to.bias = bo + i * C_;
        to.Df = dpj; to.Db = nullptr; to.dBatch = (long long)T_ * C_; to.ldd = C_;
        to.M = T_; to.N = C_; to.Kd = C_; to.nShift = 1;
        to.alpha = 1.f; to.flags = 0; to.tilesM = T_ / 64; to.tileBase = 0;
        int totO = (T_ / 64) * (C_ / 64);
        gemm_kernel<<<dim3((totO + 3) / 4, B_), 256, 0, stream>>>(to, to, to, 1, totO);

        ln_kernel<<<dim3(B_ * T_ / 4), 256, 0, stream>>>(xf, dpj, xb, g1 + i * C_, be1 + i * C_);

        // ---- conv1: 192 -> 768, K=3, ReLU ----
        GemmTask t1{};
        t1.A = xb; t1.aBatch = (long long)T_ * C_; t1.lda = C_;
        t1.B = r1 + (size_t)i * KW * FC_ * C_; t1.bBatch = 0; t1.ldb = C_;
        t1.segB = (long long)FC_ * C_;
        t1.bias = fb1 + i * FC_;
        t1.Df = nullptr; t1.Db = hh; t1.dBatch = (long long)T_ * FC_; t1.ldd = FC_;
        t1.M = T_; t1.N = FC_; t1.Kd = C_; t1.nShift = 3;
        t1.alpha = 1.f; t1.flags = 1; t1.tilesM = T_ / 64; t1.tileBase = 0;
        int tot1 = (T_ / 64) * (FC_ / 64);
        gemm_kernel<<<dim3((tot1 + 3) / 4, B_), 256, 0, stream>>>(t1, t1, t1, 1, tot1);

        // ---- conv2: 768 -> 192, K=3 (fp32 out) ----
        GemmTask t2{};
        t2.A = hh; t2.aBatch = (long long)T_ * FC_; t2.lda = FC_;
        t2.B = r2 + (size_t)i * KW * C_ * FC_; t2.bBatch = 0; t2.ldb = FC_;
        t2.segB = (long long)C_ * FC_;
        t2.bias = fb2 + i * C_;
        t2.Df = dpj; t2.Db = nullptr; t2.dBatch = (long long)T_ * C_; t2.ldd = C_;
        t2.M = T_; t2.N = C_; t2.Kd = FC_; t2.nShift = 3;
        t2.alpha = 1.f; t2.flags = 0; t2.tilesM = T_ / 64; t2.tileBase = 0;
        int tot2 = (T_ / 64) * (C_ / 64);
        gemm_kernel<<<dim3((tot2 + 3) / 4, B_), 256, 0, stream>>>(t2, t2, t2, 1, tot2);

        ln_kernel<<<dim3(B_ * T_ / 4), 256, 0, stream>>>(xf, dpj, xb, g2 + i * C_, be2 + i * C_);
    }

    out_kernel<<<dim3((B_ * C_ * T_) / 256), 256, 0, stream>>>(xf, msk, (float*)d_out);
}

// Round 16
// 1889.674 us; speedup vs baseline: 1.1010x; 1.1010x over previous
//
#include <hip/hip_runtime.h>

// ---------------- constants (match reference) ----------------
constexpr int L_ = 6, C_ = 192, FC_ = 768, H_ = 2, KC_ = 96, KW = 3, W_ = 4;
constexpr int B_ = 4, T_ = 2048;
constexpr int NC_ = 4, CS_ = T_ / NC_;   // split-S chunks for attention
constexpr float SCALE_ = 0.102062072615965696f; // 96^-0.5
constexpr float MB_ = 16.0f;             // fixed softmax rebase (overflow at S>104)

typedef unsigned short u16;
typedef unsigned int u32;
typedef short s16x8 __attribute__((ext_vector_type(8)));
typedef float f32x4 __attribute__((ext_vector_type(4)));
struct alignas(16) U4 { u32 x, y, z, w; };

#define MEMFENCE asm volatile("" ::: "memory")

// ---------------- static device scratch ----------------
__device__ alignas(256) float g_xf [B_ * T_ * C_];    // fp32 residual [B][T][C]
__device__ alignas(256) u16   g_xb [B_ * T_ * C_];    // bf16 residual
__device__ alignas(256) u16   g_qt [B_ * T_ * C_];    // q (pre-scaled) [B][T][C]
__device__ alignas(256) u16   g_kt [B_ * T_ * C_];    // k [B][T][C]
__device__ alignas(256) u16   g_vv [B_ * T_ * C_];    // v [B][C][T]
__device__ alignas(256) u16   g_aob[B_ * T_ * C_];    // attn out bf16
__device__ alignas(256) float g_dpj[B_ * T_ * C_];    // fp32 delta
__device__ alignas(256) u16   g_hh [B_ * T_ * FC_];   // FFN hidden bf16
__device__ alignas(256) u16   g_wq [L_ * C_ * C_];    // bf16 weights
__device__ alignas(256) u16   g_wk [L_ * C_ * C_];
__device__ alignas(256) u16   g_wv [L_ * C_ * C_];
__device__ alignas(256) u16   g_wo [L_ * C_ * C_];
__device__ alignas(256) u16   g_r1 [L_ * KW * FC_ * C_];  // conv1 repacked [k][f][c]
__device__ alignas(256) u16   g_r2 [L_ * KW * C_ * FC_];  // conv2 repacked [k][o][f]
// attention split-S partials: part = ((b*H+h)*128+strip)*NC+chunk
__device__ alignas(256) float g_Op [B_ * H_ * 128 * NC_ * 16 * KC_]; // 25 MB
__device__ alignas(256) float g_ml [B_ * H_ * 128 * NC_ * 16];       // l per row
// per-layer precomputed relative terms: [B][H][T][9]
__device__ alignas(256) float g_rqk[B_ * H_ * T_ * 9];  // q . erk_j
__device__ alignas(256) float g_wds[B_ * H_ * T_ * 9];  // q . k_{t+j-4} + rqk (-1e30 OOB)

#define DEV static __device__ __forceinline__

DEV float b2f(u16 v) { return __builtin_bit_cast(float, (u32)(((u32)v) << 16)); }
DEV u16 f2b(float f) {
    u32 u = __builtin_bit_cast(u32, f);
    u32 r = (u + 0x7FFFu + ((u >> 16) & 1u)) >> 16;
    return (u16)r;
}
DEV f32x4 mfma16(U4 a, U4 b, f32x4 c) {
    return __builtin_amdgcn_mfma_f32_16x16x32_bf16(
        __builtin_bit_cast(s16x8, a), __builtin_bit_cast(s16x8, b), c, 0, 0, 0);
}

// ---------------- proj weights f32 -> bf16 (same layout) --------------------
__global__ void convw_kernel(const float* __restrict__ wq, const float* __restrict__ wk,
                             const float* __restrict__ wv, const float* __restrict__ wo,
                             u16* __restrict__ dq, u16* __restrict__ dk,
                             u16* __restrict__ dv, u16* __restrict__ dwo) {
    const int NW = L_ * C_ * C_;
    int i = blockIdx.x * 256 + threadIdx.x;
    int which = i / NW, j = i - which * NW;
    const float* s = (which == 0) ? wq : (which == 1) ? wk : (which == 2) ? wv : wo;
    u16* d = (which == 0) ? dq : (which == 1) ? dk : (which == 2) ? dv : dwo;
    d[j] = f2b(s[j]);
}

// ---------------- conv weights f32 -> bf16, contiguous-c per tap ------------
__global__ void repack_kernel(const float* __restrict__ fw1, const float* __restrict__ fw2,
                              u16* __restrict__ r1, u16* __restrict__ r2) {
    int i = blockIdx.x * 256 + threadIdx.x;
    const int E1 = L_ * KW * FC_ * C_;
    if (i < E1) {
        int c = i % C_; int tmp = i / C_;
        int f = tmp % FC_; tmp /= FC_;
        int k = tmp % KW; int l = tmp / KW;
        r1[i] = f2b(fw1[((l * FC_ + f) * C_ + c) * KW + k]);
    } else {
        int j = i - E1;
        int f = j % FC_; int tmp = j / FC_;
        int o = tmp % C_; tmp /= C_;
        int k = tmp % KW; int l = tmp / KW;
        r2[j] = f2b(fw2[((l * C_ + o) * FC_ + f) * KW + k]);
    }
}

// ---------------- init: x[B,C,T] f32 -> xf fp32 / xb bf16 [B,T,C] (masked) --
__global__ void init_kernel(const float* __restrict__ x, const float* __restrict__ msk,
                            float* __restrict__ xf, u16* __restrict__ xb) {
    int i = blockIdx.x * 256 + threadIdx.x;
    int c = i % C_; int tmp = i / C_; int t = tmp % T_; int b = tmp / T_;
    float v = x[((long long)b * C_ + c) * T_ + t] * msk[b * T_ + t];
    xf[i] = v; xb[i] = f2b(v);
}

// ---------------- out: xf [B,T,C] -> out[B,C,T] FP32 (masked) ---------------
__global__ void out_kernel(const float* __restrict__ xf, const float* __restrict__ msk,
                           float* __restrict__ out) {
    int i = blockIdx.x * 256 + threadIdx.x;
    int t = i % T_; int tmp = i / T_; int c = tmp % C_; int b = tmp / C_;
    float v = xf[((long long)b * T_ + t) * C_ + c] * msk[b * T_ + t];
    if (!(v == v)) v = 0.0f;
    out[i] = v;
}

// ---------------- LayerNorm over C: xf = LN(xf + delta); xb = bf16(xf) ------
__global__ __launch_bounds__(256) void ln_kernel(float* __restrict__ xf,
                                                 const float* __restrict__ delta,
                                                 u16* __restrict__ xb,
                                                 const float* __restrict__ g,
                                                 const float* __restrict__ be) {
    int pos = blockIdx.x * 4 + (threadIdx.x >> 6);
    int lane = threadIdx.x & 63;
    long long base = (long long)pos * C_;
    float u[3]; float s = 0.f;
#pragma unroll
    for (int i = 0; i < 3; ++i) {
        int c = lane + i * 64;
        float v = xf[base + c] + delta[base + c];
        u[i] = v; s += v;
    }
#pragma unroll
    for (int d = 1; d < 64; d <<= 1) s += __shfl_xor(s, d, 64);
    float mean = s * (1.0f / C_);
    float ss = 0.f;
#pragma unroll
    for (int i = 0; i < 3; ++i) { float dv = u[i] - mean; ss += dv * dv; }
#pragma unroll
    for (int d = 1; d < 64; d <<= 1) ss += __shfl_xor(ss, d, 64);
    float var = fmaxf(ss * (1.0f / C_), 0.0f);
    float rs = rsqrtf(var + 1e-5f);
#pragma unroll
    for (int i = 0; i < 3; ++i) {
        int c = lane + i * 64;
        float y = (u[i] - mean) * rs * g[c] + be[c];
        xf[base + c] = y; xb[base + c] = f2b(y);
    }
}

// ---------------- generic MFMA GEMM, 32x32 wave tile, compile-time K --------
struct GemmTask {
    const u16* A; const u16* B; const float* bias;
    float* Df; u16* Db;
    long long aBatch, bBatch, dBatch, segB;
    int lda, ldb, ldd;
    int M, N;
    float alpha; int flags; // 1 = relu, 2 = bias indexed by row (else col)
    int tilesM, tileBase;
};

template <int KD, int NSHIFT>
__global__ __launch_bounds__(256) void gemm_kernel(GemmTask ta, GemmTask tb, GemmTask tc,
                                                   int nTasks, int totalTiles) {
    int wid = blockIdx.x * 4 + (threadIdx.x >> 6);
    if (wid >= totalTiles) return;
    GemmTask t = ta;
    if (nTasks > 1 && wid >= tb.tileBase) t = tb;
    if (nTasks > 2 && wid >= tc.tileBase) t = tc;
    int tid = wid - t.tileBase;
    int tm = tid % t.tilesM, tn = tid / t.tilesM;
    int z = blockIdx.y;
    int lane = threadIdx.x & 63, l15 = lane & 15, quad = lane >> 4;
    const u16* A = t.A + (long long)z * t.aBatch;
    const u16* Bb = t.B + (long long)z * t.bBatch;
    int m0 = tm * 32, n0 = tn * 32;
    f32x4 acc[2][2] = {};
    int cb = quad * 8;
#pragma unroll
    for (int sh = 0; sh < NSHIFT; ++sh) {
        int rowOff = sh - (NSHIFT >> 1);
        const u16* Bs = Bb + (long long)sh * t.segB;
        int r0 = m0 + l15 + rowOff;
        int r1i = r0 + 16;
        bool v0 = (unsigned)r0 < (unsigned)t.M;
        bool v1 = (unsigned)r1i < (unsigned)t.M;
        const u16* ar0 = A + (long long)r0 * t.lda + cb;
        const u16* ar1 = A + (long long)r1i * t.lda + cb;
        const u16* br0 = Bs + (long long)(n0 + l15) * t.ldb + cb;
        const u16* br1 = br0 + (long long)16 * t.ldb;
#pragma unroll
        for (int kk = 0; kk < KD; kk += 32) {
            U4 a0{0, 0, 0, 0}, a1{0, 0, 0, 0};
            if (v0) a0 = *(const U4*)(ar0 + kk);
            if (v1) a1 = *(const U4*)(ar1 + kk);
            U4 b0 = *(const U4*)(br0 + kk);
            U4 b1 = *(const U4*)(br1 + kk);
            acc[0][0] = mfma16(a0, b0, acc[0][0]);
            acc[0][1] = mfma16(a0, b1, acc[0][1]);
            acc[1][0] = mfma16(a1, b0, acc[1][0]);
            acc[1][1] = mfma16(a1, b1, acc[1][1]);
        }
    }
#pragma unroll
    for (int mb = 0; mb < 2; ++mb)
#pragma unroll
        for (int nb = 0; nb < 2; ++nb) {
            int col = n0 + nb * 16 + l15;
#pragma unroll
            for (int reg = 0; reg < 4; ++reg) {
                int row = m0 + mb * 16 + quad * 4 + reg;
                float bb = t.bias[(t.flags & 2) ? row : col];
                float val = (acc[mb][nb][reg] + bb) * t.alpha;
                if (t.flags & 1) val = fmaxf(val, 0.0f);
                long long o = (long long)z * t.dBatch + (long long)row * t.ldd + col;
                if (t.Df) t.Df[o] = val; else t.Db[o] = f2b(val);
            }
        }
}

// ---------------- per-layer relative-term precompute ----------------
__global__ __launch_bounds__(256) void rqwd_kernel(const u16* __restrict__ q,
                                                   const u16* __restrict__ k,
                                                   const float* __restrict__ erk,
                                                   float* __restrict__ rqk,
                                                   float* __restrict__ wds) {
    int i = blockIdx.x * 256 + threadIdx.x;        // over B*H*T*9
    int j = i % 9; int tmp = i / 9;
    int t = tmp % T_; tmp /= T_;
    int h = tmp & 1; int b = tmp >> 1;
    const u16* qr = q + ((long long)b * T_ + t) * C_ + h * KC_;
    const float* er = erk + j * KC_;
    float s1 = 0.f;
    for (int c = 0; c < KC_; ++c) s1 += b2f(qr[c]) * er[c];
    rqk[i] = s1;
    int s2 = t + j - W_;
    float wd = -1e30f;
    if (s2 >= 0 && s2 < T_) {
        const u16* kr = k + ((long long)b * T_ + s2) * C_ + h * KC_;
        float d = 0.f;
        for (int c = 0; c < KC_; ++c) d += b2f(qr[c]) * b2f(kr[c]);
        wd = d + s1;
    }
    wds[i] = wd;
}

// ---------------- split-S attention, fixed-rebase, compiler-fenced ----------
__global__ __launch_bounds__(256) void attn_part(const u16* __restrict__ q,
                                                 const u16* __restrict__ k,
                                                 const u16* __restrict__ v,
                                                 float* __restrict__ Op,
                                                 float* __restrict__ ml,
                                                 const float* __restrict__ rqk) {
    __shared__ alignas(64) u16 Pl[4][16][48];
    __shared__ float rqc[4][16][12];

    int wib = threadIdx.x >> 6;
    int lane = threadIdx.x & 63, l15 = lane & 15, quad = lane >> 4;
    int w = blockIdx.x * 4 + wib;                 // ((b*H+h)*128+strip)*NC+chunk
    int chunk = w & (NC_ - 1);
    int strip = (w >> 2) & 127;
    int h = (w >> 9) & 1;
    int b = w >> 10;
    int t0 = strip * 16;
    int sbase = chunk * CS_;
    const u16* qp = q + ((long long)b * T_ + t0) * C_ + h * KC_;
    const u16* kp = k + (long long)b * T_ * C_ + h * KC_;
    const u16* vp = v + ((long long)b * C_ + h * KC_) * T_;

    const float* rq = rqk + (((long long)(b * H_ + h)) * T_ + t0) * 9;
    for (int idx = lane; idx < 144; idx += 64) {
        int r = idx / 9, j = idx - r * 9;
        rqc[wib][r][j] = rq[idx];
    }
    __syncthreads();   // once, outside hot loop

    U4 aq0 = *(const U4*)(qp + l15 * C_ + quad * 8);
    U4 aq1 = *(const U4*)(qp + l15 * C_ + 32 + quad * 8);
    U4 aq2 = *(const U4*)(qp + l15 * C_ + 64 + quad * 8);
    U4 ones{0x3F803F80u, 0x3F803F80u, 0x3F803F80u, 0x3F803F80u}; // bf16 1.0 x8

    f32x4 O[7] = {};   // [0..5] = output cols, [6] = row-sum l

    for (int s0 = sbase; s0 < sbase + CS_; s0 += 32) {
        f32x4 S[2];
#pragma unroll
        for (int sub = 0; sub < 2; ++sub) {
            const u16* kr = kp + (long long)(s0 + sub * 16 + l15) * C_ + quad * 8;
            f32x4 a = {0.f, 0.f, 0.f, 0.f};
            a = mfma16(aq0, *(const U4*)(kr), a);
            a = mfma16(aq1, *(const U4*)(kr + 32), a);
            a = mfma16(aq2, *(const U4*)(kr + 64), a);
            int s = s0 + sub * 16 + l15;
#pragma unroll
            for (int reg = 0; reg < 4; ++reg) {
                int t = t0 + quad * 4 + reg;
                int d = s - t;
                if (d >= -W_ && d <= W_) a[reg] += rqc[wib][quad * 4 + reg][d + W_];
            }
            S[sub] = a;
        }
#pragma unroll
        for (int sub = 0; sub < 2; ++sub)
#pragma unroll
            for (int reg = 0; reg < 4; ++reg)
                Pl[wib][quad * 4 + reg][sub * 16 + l15] = f2b(__expf(S[sub][reg] - MB_));
        MEMFENCE;   // RAW: stores above must not sink below the load
        U4 pf = *(const U4*)(&Pl[wib][l15][quad * 8]);
        MEMFENCE;   // WAR: next iteration's stores must not hoist above the load
#pragma unroll
        for (int dt = 0; dt < 6; ++dt) {
            const u16* vr = vp + (long long)(dt * 16 + l15) * T_ + s0 + quad * 8;
            O[dt] = mfma16(pf, *(const U4*)(vr), O[dt]);
        }
        O[6] = mfma16(pf, ones, O[6]);
    }

    float* Od = Op + (long long)w * 16 * KC_;
#pragma unroll
    for (int dt = 0; dt < 6; ++dt) {
        int col = dt * 16 + l15;
#pragma unroll
        for (int reg = 0; reg < 4; ++reg) {
            int row = quad * 4 + reg;
            Od[row * KC_ + col] = O[dt][reg];
        }
    }
    if (l15 == 0) {
#pragma unroll
        for (int reg = 0; reg < 4; ++reg)
            ml[(long long)w * 16 + quad * 4 + reg] = O[6][reg];
    }
}

// ---------------- combine (plain sum) + window-V epilogue -------------------
__global__ __launch_bounds__(256) void attn_comb(const float* __restrict__ Op,
                                                 const float* __restrict__ ml,
                                                 const float* __restrict__ wds,
                                                 u16* __restrict__ ao,
                                                 const float* __restrict__ erv) {
    __shared__ float lrow[4][16];
    __shared__ float pw[4][16][12];

    int wib = threadIdx.x >> 6, lane = threadIdx.x & 63;
    int w = blockIdx.x * 4 + wib;                 // (b*H+h)*128+strip
    int strip = w & 127, h = (w >> 7) & 1, b = w >> 8;
    int t0 = strip * 16;
    u16* aop = ao + ((long long)b * T_ + t0) * C_ + h * KC_;

    if (lane < 16) {
        float l = 0.f;
#pragma unroll
        for (int c4 = 0; c4 < NC_; ++c4)
            l += ml[(long long)(w * NC_ + c4) * 16 + lane];
        lrow[wib][lane] = l;
    }
    const float* wd = wds + (((long long)(b * H_ + h)) * T_ + t0) * 9;
    for (int idx = lane; idx < 144; idx += 64) {
        int r = idx / 9, j = idx - r * 9;
        pw[wib][r][j] = __expf(wd[idx] - MB_);    // 0 for OOB (-1e30)
    }
    __syncthreads();

    const float* Ob = Op + (long long)(w * NC_) * 16 * KC_;
    for (int idx = lane; idx < 16 * KC_; idx += 64) {
        int r = idx / KC_, c = idx - r * KC_;
        float acc = 0.f;
#pragma unroll
        for (int c4 = 0; c4 < NC_; ++c4)
            acc += Ob[(long long)c4 * 16 * KC_ + idx];
#pragma unroll
        for (int j = 0; j < 9; ++j) acc += pw[wib][r][j] * erv[j * KC_ + c];
        aop[(long long)r * C_ + c] = f2b(acc / lrow[wib][r]);
    }
}

// ---------------- host orchestration ----------------
extern "C" void kernel_launch(void* const* d_in, const int* in_sizes, int n_in,
                              void* d_out, int out_size, void* d_ws, size_t ws_size,
                              hipStream_t stream) {
    const float* x   = (const float*)d_in[0];
    const float* msk = (const float*)d_in[1];
    const float* Wq  = (const float*)d_in[2];
    const float* bq  = (const float*)d_in[3];
    const float* Wk  = (const float*)d_in[4];
    const float* bk  = (const float*)d_in[5];
    const float* Wv  = (const float*)d_in[6];
    const float* bv  = (const float*)d_in[7];
    const float* Wo  = (const float*)d_in[8];
    const float* bo  = (const float*)d_in[9];
    const float* erk = (const float*)d_in[10];
    const float* erv = (const float*)d_in[11];
    const float* g1  = (const float*)d_in[12];
    const float* be1 = (const float*)d_in[13];
    const float* fw1 = (const float*)d_in[14];
    const float* fb1 = (const float*)d_in[15];
    const float* fw2 = (const float*)d_in[16];
    const float* fb2 = (const float*)d_in[17];
    const float* g2  = (const float*)d_in[18];
    const float* be2 = (const float*)d_in[19];

    float *xf, *dpj, *Op, *ml, *rqk, *wds;
    u16 *xb, *qt, *kt, *vv, *aob, *hh, *wqb, *wkb, *wvb, *wob, *r1, *r2;
    hipGetSymbolAddress((void**)&xf,  HIP_SYMBOL(g_xf));
    hipGetSymbolAddress((void**)&xb,  HIP_SYMBOL(g_xb));
    hipGetSymbolAddress((void**)&qt,  HIP_SYMBOL(g_qt));
    hipGetSymbolAddress((void**)&kt,  HIP_SYMBOL(g_kt));
    hipGetSymbolAddress((void**)&vv,  HIP_SYMBOL(g_vv));
    hipGetSymbolAddress((void**)&aob, HIP_SYMBOL(g_aob));
    hipGetSymbolAddress((void**)&dpj, HIP_SYMBOL(g_dpj));
    hipGetSymbolAddress((void**)&hh,  HIP_SYMBOL(g_hh));
    hipGetSymbolAddress((void**)&wqb, HIP_SYMBOL(g_wq));
    hipGetSymbolAddress((void**)&wkb, HIP_SYMBOL(g_wk));
    hipGetSymbolAddress((void**)&wvb, HIP_SYMBOL(g_wv));
    hipGetSymbolAddress((void**)&wob, HIP_SYMBOL(g_wo));
    hipGetSymbolAddress((void**)&r1,  HIP_SYMBOL(g_r1));
    hipGetSymbolAddress((void**)&r2,  HIP_SYMBOL(g_r2));
    hipGetSymbolAddress((void**)&Op,  HIP_SYMBOL(g_Op));
    hipGetSymbolAddress((void**)&ml,  HIP_SYMBOL(g_ml));
    hipGetSymbolAddress((void**)&rqk, HIP_SYMBOL(g_rqk));
    hipGetSymbolAddress((void**)&wds, HIP_SYMBOL(g_wds));

    convw_kernel<<<dim3(4 * L_ * C_ * C_ / 256), 256, 0, stream>>>(Wq, Wk, Wv, Wo,
                                                                   wqb, wkb, wvb, wob);
    repack_kernel<<<dim3(2 * L_ * KW * FC_ * C_ / 256), 256, 0, stream>>>(fw1, fw2, r1, r2);
    init_kernel<<<dim3((B_ * T_ * C_) / 256), 256, 0, stream>>>(x, msk, xf, xb);

    for (int i = 0; i < L_; ++i) {
        const float* erkl = erk + (size_t)i * (2 * W_ + 1) * KC_;
        const float* ervl = erv + (size_t)i * (2 * W_ + 1) * KC_;

        // ---- fused q/k/v projections (3 tasks, one launch) ----
        GemmTask tq{};
        tq.A = xb; tq.aBatch = (long long)T_ * C_; tq.lda = C_;
        tq.B = wqb + (size_t)i * C_ * C_; tq.bBatch = 0; tq.ldb = C_; tq.segB = 0;
        tq.bias = bq + i * C_;
        tq.Df = nullptr; tq.Db = qt; tq.dBatch = (long long)T_ * C_; tq.ldd = C_;
        tq.M = T_; tq.N = C_;
        tq.alpha = SCALE_; tq.flags = 0; tq.tilesM = T_ / 32; tq.tileBase = 0;

        GemmTask tkk = tq;
        tkk.B = wkb + (size_t)i * C_ * C_; tkk.bias = bk + i * C_;
        tkk.Db = kt; tkk.alpha = 1.f;
        tkk.tileBase = (T_ / 32) * (C_ / 32);

        GemmTask tv{};
        tv.A = wvb + (size_t)i * C_ * C_; tv.aBatch = 0; tv.lda = C_;
        tv.B = xb; tv.bBatch = (long long)T_ * C_; tv.ldb = C_; tv.segB = 0;
        tv.bias = bv + i * C_;
        tv.Df = nullptr; tv.Db = vv; tv.dBatch = (long long)C_ * T_; tv.ldd = T_;
        tv.M = C_; tv.N = T_;
        tv.alpha = 1.f; tv.flags = 2; tv.tilesM = C_ / 32;
        tv.tileBase = 2 * (T_ / 32) * (C_ / 32);

        int totQKV = 3 * (T_ / 32) * (C_ / 32);
        gemm_kernel<192, 1><<<dim3(totQKV / 4, B_), 256, 0, stream>>>(tq, tkk, tv, 3, totQKV);

        // ---- rel-term precompute + split-S attention ----
        rqwd_kernel<<<dim3(B_ * H_ * T_ * 9 / 256), 256, 0, stream>>>(qt, kt, erkl, rqk, wds);
        attn_part<<<dim3(B_ * H_ * 128 * NC_ / 4), 256, 0, stream>>>(qt, kt, vv, Op, ml, rqk);
        attn_comb<<<dim3(B_ * H_ * 128 / 4), 256, 0, stream>>>(Op, ml, wds, aob, ervl);

        // ---- output projection (fp32 out) ----
        GemmTask to{};
        to.A = aob; to.aBatch = (long long)T_ * C_; to.lda = C_;
        to.B = wob + (size_t)i * C_ * C_; to.bBatch = 0; to.ldb = C_; to.segB = 0;
        to.bias = bo + i * C_;
        to.Df = dpj; to.Db = nullptr; to.dBatch = (long long)T_ * C_; to.ldd = C_;
        to.M = T_; to.N = C_;
        to.alpha = 1.f; to.flags = 0; to.tilesM = T_ / 32; to.tileBase = 0;
        int totO = (T_ / 32) * (C_ / 32);
        gemm_kernel<192, 1><<<dim3(totO / 4, B_), 256, 0, stream>>>(to, to, to, 1, totO);

        ln_kernel<<<dim3(B_ * T_ / 4), 256, 0, stream>>>(xf, dpj, xb, g1 + i * C_, be1 + i * C_);

        // ---- conv1: 192 -> 768, K=3, ReLU ----
        GemmTask t1{};
        t1.A = xb; t1.aBatch = (long long)T_ * C_; t1.lda = C_;
        t1.B = r1 + (size_t)i * KW * FC_ * C_; t1.bBatch = 0; t1.ldb = C_;
        t1.segB = (long long)FC_ * C_;
        t1.bias = fb1 + i * FC_;
        t1.Df = nullptr; t1.Db = hh; t1.dBatch = (long long)T_ * FC_; t1.ldd = FC_;
        t1.M = T_; t1.N = FC_;
        t1.alpha = 1.f; t1.flags = 1; t1.tilesM = T_ / 32; t1.tileBase = 0;
        int tot1 = (T_ / 32) * (FC_ / 32);
        gemm_kernel<192, 3><<<dim3(tot1 / 4, B_), 256, 0, stream>>>(t1, t1, t1, 1, tot1);

        // ---- conv2: 768 -> 192, K=3 (fp32 out) ----
        GemmTask t2{};
        t2.A = hh; t2.aBatch = (long long)T_ * FC_; t2.lda = FC_;
        t2.B = r2 + (size_t)i * KW * C_ * FC_; t2.bBatch = 0; t2.ldb = FC_;
        t2.segB = (long long)C_ * FC_;
        t2.bias = fb2 + i * C_;
        t2.Df = dpj; t2.Db = nullptr; t2.dBatch = (long long)T_ * C_; t2.ldd = C_;
        t2.M = T_; t2.N = C_;
        t2.alpha = 1.f; t2.flags = 0; t2.tilesM = T_ / 32; t2.tileBase = 0;
        int tot2 = (T_ / 32) * (C_ / 32);
        gemm_kernel<768, 3><<<dim3(tot2 / 4, B_), 256, 0, stream>>>(t2, t2, t2, 1, tot2);

        ln_kernel<<<dim3(B_ * T_ / 4), 256, 0, stream>>>(xf, dpj, xb, g2 + i * C_, be2 + i * C_);
    }

    out_kernel<<<dim3((B_ * C_ * T_) / 256), 256, 0, stream>>>(xf, msk, (float*)d_out);
}